// Round 1
// baseline (2374.663 us; speedup 1.0000x reference)
//
#include <hip/hip_runtime.h>
#include <stdint.h>

// TopK activation: relu(x), keep top-k per row of 32768, zero the rest.
// One 1024-thread block per row; data in registers (32 elems/thread).
//
// v2: single 2048-bin radix round (top-11 bits) + exact candidate
// collect/rank-select (handles ties by lowest index in one shot).
// Fallback refinement rounds (22 bits, 32 bits, then index-histogram)
// keep exactness for degenerate inputs. Bin-major 4-replica histogram
// (replicas of a bin in 4 different banks, r = tid&3) kills in-wave
// same-address serialization. Bulk zero-stores issued before the
// select phase to overlap the write stream with selection.

#define NT    1024
#define NCOL  32768
#define VPT   8          // uint4 (4 elems) per thread -> 32 elems/thread
#define NB    2048       // histogram bins per round
#define REP   4          // histogram replicas (bin-major: 4 banks per bin)
#define CAP   1024       // candidate list capacity

__global__ __launch_bounds__(NT) void topk_select_kernel(
        const float* __restrict__ x, const int* __restrict__ kptr,
        float* __restrict__ out)
{
    __shared__ uint32_t hist[NB][REP];   // bin-major: bin's replicas adjacent
    __shared__ uint32_t red[NB];         // replica-reduced histogram
    __shared__ uint64_t cand[CAP];       // packed (key<<32 | (32767-idx))
    __shared__ int s_found, s_B, s_kth, s_cnt, s_nc;
    __shared__ uint32_t s_thr;
    __shared__ int s_cut;

    const int tid  = threadIdx.x;
    const int lane = tid & 63;
    const int wave = tid >> 6;
    const size_t base = (size_t)blockIdx.x * NCOL;

    int k = *kptr;
    if (k > NCOL) k = NCOL;

    const uint4* xv = (const uint4*)(x + base);
    uint4*       ov = (uint4*)(out + base);

    if (k <= 0) {   // uniform across block: safe early-out, write zeros
        #pragma unroll
        for (int j = 0; j < VPT; ++j)
            ov[j * NT + tid] = make_uint4(0u, 0u, 0u, 0u);
        return;
    }

    // ---- load row, map to order-preserving keys (<=0 -> 0) ----
    uint4 va[VPT];
    #pragma unroll
    for (int j = 0; j < VPT; ++j) va[j] = xv[j * NT + tid];
    #pragma unroll
    for (int j = 0; j < VPT; ++j) {
        uint32_t* p = (uint32_t*)&va[j];
        #pragma unroll
        for (int c = 0; c < 4; ++c) {
            uint32_t u = p[c];
            p[c] = ((int)u > 0) ? u : 0u;   // positive float bits are monotonic
        }
    }
    if (tid == 0) s_nc = 0;

    int kth = k;                  // rank remaining within current candidate set
    uint32_t p11 = 0u, p22 = 0u, thrx = 0u, B3 = 0u;
    uint32_t binfloor = 1u;       // elements below this are certainly zeroed
    uint32_t thr = 0u;            // final exact bits of k-th largest
    int cut = -1;                 // tie cut index (keep idx <= cut at == thr)
    int mode = 4;                 // 4 = thr/cut decided; 0..3 = collect mode
    const int rrep = tid & (REP - 1);

    for (int round = 0; round < 4; ++round) {
        // clear hist (2048 uint4 = 8192 words)
        {
            uint4* h4 = (uint4*)&hist[0][0];
            h4[tid]      = make_uint4(0u, 0u, 0u, 0u);
            h4[tid + NT] = make_uint4(0u, 0u, 0u, 0u);
        }
        __syncthreads();

        // ---- accumulate histogram (specialized per round) ----
        if (round == 0) {
            #pragma unroll
            for (int j = 0; j < VPT; ++j) {
                const uint32_t* p = (const uint32_t*)&va[j];
                #pragma unroll
                for (int c = 0; c < 4; ++c) {
                    uint32_t vv = p[c];
                    if (vv) atomicAdd(&hist[vv >> 21][rrep], 1u);
                }
            }
        } else if (round == 1) {
            #pragma unroll
            for (int j = 0; j < VPT; ++j) {
                const uint32_t* p = (const uint32_t*)&va[j];
                #pragma unroll
                for (int c = 0; c < 4; ++c) {
                    uint32_t vv = p[c];
                    if (vv && (vv >> 21) == p11)
                        atomicAdd(&hist[(vv >> 10) & 0x7FFu][rrep], 1u);
                }
            }
        } else if (round == 2) {
            #pragma unroll
            for (int j = 0; j < VPT; ++j) {
                const uint32_t* p = (const uint32_t*)&va[j];
                #pragma unroll
                for (int c = 0; c < 4; ++c) {
                    uint32_t vv = p[c];
                    if (vv && (vv >> 10) == p22)
                        atomicAdd(&hist[vv & 0x3FFu][rrep], 1u);
                }
            }
        } else {  // round 3: index histogram among exact ties (ascending idx)
            #pragma unroll
            for (int j = 0; j < VPT; ++j) {
                const uint32_t* p = (const uint32_t*)&va[j];
                #pragma unroll
                for (int c = 0; c < 4; ++c) {
                    uint32_t vv = p[c];
                    int idx = j * 4096 + tid * 4 + c;
                    if (vv == thrx)
                        atomicAdd(&hist[(uint32_t)(32767 - idx) >> 4][rrep], 1u);
                }
            }
        }
        __syncthreads();

        // ---- replica reduce (all threads, conflict-free b128 reads) ----
        {
            uint4 h0 = *(const uint4*)&hist[tid][0];
            uint4 h1 = *(const uint4*)&hist[tid + NT][0];
            red[tid]      = h0.x + h0.y + h0.z + h0.w;
            red[tid + NT] = h1.x + h1.y + h1.z + h1.w;
        }
        __syncthreads();

        // ---- wave0: suffix-scan 2048 bins, find crossing bin ----
        if (wave == 0) {
            uint32_t s = 0;
            for (int i = 0; i < 32; ++i) {
                int b = lane * 32 + ((i + lane) & 31);   // swizzle: 2/bank
                s += red[b];
            }
            uint32_t suf = s;
            #pragma unroll
            for (int d = 1; d < 64; d <<= 1) {
                uint32_t t2 = __shfl_down(suf, d);
                if (lane + d < 64) suf += t2;
            }
            uint32_t t1  = __shfl_down(suf, 1);
            uint32_t nxt = (lane == 63) ? 0u : t1;
            bool cond = (suf >= (uint32_t)kth) && (nxt < (uint32_t)kth);
            unsigned long long mask = __ballot(cond);
            if (mask == 0ull) {
                if (lane == 0) s_found = 0;   // fewer than kth active values
            } else {
                int G = __ffsll(mask) - 1;
                uint32_t cntG = __shfl(nxt, G);   // count in groups above G
                uint32_t h2 = 0;
                if (lane < 32) h2 = red[G * 32 + lane];
                uint32_t suf2 = h2;
                #pragma unroll
                for (int d = 1; d < 64; d <<= 1) {
                    uint32_t t2 = __shfl_down(suf2, d);
                    if (lane + d < 64) suf2 += t2;
                }
                uint32_t t3   = __shfl_down(suf2, 1);
                uint32_t nxt2 = (lane == 63) ? 0u : t3;
                uint32_t ts   = cntG + suf2;
                uint32_t tsn  = cntG + nxt2;
                bool cond2 = (lane < 32) && (ts >= (uint32_t)kth) && (tsn < (uint32_t)kth);
                unsigned long long m2 = __ballot(cond2);
                int l = __ffsll(m2) - 1;
                uint32_t ngt  = __shfl(tsn, l);          // strictly-above count
                uint32_t cbin = __shfl(suf2 - nxt2, l);  // count at selected bin
                if (lane == 0) {
                    s_found = 1;
                    s_B   = G * 32 + l;
                    s_kth = kth - (int)ngt;
                    s_cnt = (int)cbin;
                }
            }
        }
        __syncthreads();

        // ---- uniform state update / early exit ----
        if (!s_found) { thr = 0u; cut = -1; mode = 4; break; }
        kth = s_kth;
        {
            const int B = s_B, cnt = s_cnt;
            if (round == 0) {
                p11 = (uint32_t)B;
                binfloor = p11 << 21;
                if (cnt <= CAP) { mode = 0; break; }
            } else if (round == 1) {
                p22 = (p11 << 11) | (uint32_t)B;
                if (cnt <= CAP) { mode = 1; break; }
            } else if (round == 2) {
                thrx = (p22 << 10) | (uint32_t)B;
                if (cnt == kth) { thr = thrx; cut = 0x7FFFFFFF; mode = 4; break; }
                if (cnt <= CAP) { mode = 2; break; }
            } else {
                B3 = (uint32_t)B;   // idx-bin; <=16 candidates
                mode = 3;
            }
        }
    }

    // ---- bulk store: groups entirely below the selected bin floor are
    // certainly zero; issue these stores NOW so they overlap the select ----
    uint32_t defer = 0u;
    #pragma unroll
    for (int j = 0; j < VPT; ++j) {
        const uint32_t* p = (const uint32_t*)&va[j];
        bool anyhi = (p[0] >= binfloor) || (p[1] >= binfloor) ||
                     (p[2] >= binfloor) || (p[3] >= binfloor);
        if (anyhi) defer |= (1u << j);
        else       ov[j * NT + tid] = make_uint4(0u, 0u, 0u, 0u);
    }

    // ---- candidate collect + exact rank select (common path: mode 0) ----
    if (mode != 4) {
        if (mode == 0) {
            #pragma unroll
            for (int j = 0; j < VPT; ++j) {
                if (!((defer >> j) & 1u)) continue;
                const uint32_t* p = (const uint32_t*)&va[j];
                #pragma unroll
                for (int c = 0; c < 4; ++c) {
                    uint32_t vv = p[c];
                    if (vv && (vv >> 21) == p11) {
                        int slot = atomicAdd(&s_nc, 1);
                        int idx = j * 4096 + tid * 4 + c;
                        if (slot < CAP)
                            cand[slot] = ((uint64_t)vv << 32) | (uint32_t)(32767 - idx);
                    }
                }
            }
        } else if (mode == 1) {
            #pragma unroll
            for (int j = 0; j < VPT; ++j) {
                if (!((defer >> j) & 1u)) continue;
                const uint32_t* p = (const uint32_t*)&va[j];
                #pragma unroll
                for (int c = 0; c < 4; ++c) {
                    uint32_t vv = p[c];
                    if (vv && (vv >> 10) == p22) {
                        int slot = atomicAdd(&s_nc, 1);
                        int idx = j * 4096 + tid * 4 + c;
                        if (slot < CAP)
                            cand[slot] = ((uint64_t)vv << 32) | (uint32_t)(32767 - idx);
                    }
                }
            }
        } else if (mode == 2) {
            #pragma unroll
            for (int j = 0; j < VPT; ++j) {
                if (!((defer >> j) & 1u)) continue;
                const uint32_t* p = (const uint32_t*)&va[j];
                #pragma unroll
                for (int c = 0; c < 4; ++c) {
                    uint32_t vv = p[c];
                    if (vv == thrx) {
                        int slot = atomicAdd(&s_nc, 1);
                        int idx = j * 4096 + tid * 4 + c;
                        if (slot < CAP)
                            cand[slot] = ((uint64_t)vv << 32) | (uint32_t)(32767 - idx);
                    }
                }
            }
        } else {  // mode 3: exact ties restricted to selected idx-bin (<=16)
            #pragma unroll
            for (int j = 0; j < VPT; ++j) {
                if (!((defer >> j) & 1u)) continue;
                const uint32_t* p = (const uint32_t*)&va[j];
                #pragma unroll
                for (int c = 0; c < 4; ++c) {
                    uint32_t vv = p[c];
                    int idx = j * 4096 + tid * 4 + c;
                    if (vv == thrx && ((uint32_t)(32767 - idx) >> 4) == B3) {
                        int slot = atomicAdd(&s_nc, 1);
                        if (slot < CAP)
                            cand[slot] = ((uint64_t)vv << 32) | (uint32_t)(32767 - idx);
                    }
                }
            }
        }
        __syncthreads();

        // rank by (value desc, idx asc) == packed u64 desc; unique keys.
        int n = s_nc; if (n > CAP) n = CAP;
        if (tid < n) {
            const uint64_t ci = cand[tid];
            int rank = 0;
            for (int j2 = 0; j2 < n; ++j2)          // broadcast reads
                rank += (cand[j2] > ci) ? 1 : 0;
            if (rank == kth - 1) {                  // the last kept element
                s_thr = (uint32_t)(ci >> 32);
                s_cut = 32767 - (int)(ci & 0xFFFFu);
            }
        }
        __syncthreads();
        thr = s_thr;
        cut = s_cut;
    }

    // ---- write deferred groups with the exact keep rule ----
    #pragma unroll
    for (int j = 0; j < VPT; ++j) {
        if (!((defer >> j) & 1u)) continue;
        const uint32_t* p = (const uint32_t*)&va[j];
        uint4 o;
        uint32_t* q = (uint32_t*)&o;
        #pragma unroll
        for (int c = 0; c < 4; ++c) {
            uint32_t vv = p[c];
            int idx = j * 4096 + tid * 4 + c;
            bool keep = (vv > thr) || (thr != 0u && vv == thr && idx <= cut);
            q[c] = keep ? vv : 0u;
        }
        ov[j * NT + tid] = o;
    }
}

extern "C" void kernel_launch(void* const* d_in, const int* in_sizes, int n_in,
                              void* d_out, int out_size, void* d_ws, size_t ws_size,
                              hipStream_t stream) {
    const float* x    = (const float*)d_in[0];
    const int*   kptr = (const int*)d_in[1];
    float*       out  = (float*)d_out;
    const int rows = in_sizes[0] / NCOL;
    topk_select_kernel<<<rows, NT, 0, stream>>>(x, kptr, out);
}